// Round 3
// baseline (108.471 us; speedup 1.0000x reference)
//
#include <hip/hip_runtime.h>
#include <hip/hip_bf16.h>

#define THRESH 0.05f
constexpr int B_   = 32;
constexpr int CIN  = 128;
constexpr int COUT = 256;
constexpr int HH   = 56;
constexpr int WW   = 56;
constexpr int HWSZ = HH * WW;            // 3136
constexpr int WELEM = COUT * CIN * 9;    // 294912
constexpr int PADW = 58;                 // padded spatial dim
constexpr int PSITES = PADW * PADW;      // 3364

typedef unsigned short u16;
typedef __attribute__((ext_vector_type(4))) float  f32x4;
typedef __attribute__((ext_vector_type(8))) short  s16x8;

typedef const __attribute__((address_space(1))) void* gas1;
typedef __attribute__((address_space(3))) void* las3;
#define GLOAD16(gsrc, ldst) \
    __builtin_amdgcn_global_load_lds((gas1)(gsrc), (las3)(ldst), 16, 0, 0)

static __device__ __forceinline__ u16 f2bf(float f) {
    __hip_bfloat16 h = __float2bfloat16(f);
    return *reinterpret_cast<u16*>(&h);
}

// ---------------------------------------------------------------------------
// Kernel 1: per-block maxabs partials
// ---------------------------------------------------------------------------
__global__ __launch_bounds__(256) void maxabs_part(const float* __restrict__ w,
                                                   float* __restrict__ partial) {
    int tid = threadIdx.x;
    float m = 0.0f;
    for (int i = blockIdx.x * 256 + tid; i < WELEM; i += 256 * 256)
        m = fmaxf(m, fabsf(w[i]));
    #pragma unroll
    for (int off = 32; off > 0; off >>= 1) m = fmaxf(m, __shfl_xor(m, off));
    __shared__ float s[4];
    if ((tid & 63) == 0) s[tid >> 6] = m;
    __syncthreads();
    if (tid == 0) partial[blockIdx.x] = fmaxf(fmaxf(s[0], s[1]), fmaxf(s[2], s[3]));
}

// ---------------------------------------------------------------------------
// Kernel 2: reduce + faithful ternary quantize + pack bf16 into PERMUTED layout
// Apack u16 index: ((cc*4 + cot)*64 + row)*288 + tap*32 + (g ^ ((row>>1)&3))*8 + e
//   where co = cot*64+row, ci = cc*32 + g*8 + e.
// This makes each (cc, co-tile) A-subtile a contiguous 36,864 B block whose
// linear global_load_lds image has conflict-free ds_read_b128 fragments.
// ---------------------------------------------------------------------------
__global__ __launch_bounds__(256) void quant_pack(const float* __restrict__ w,
                                                  const float* __restrict__ partial,
                                                  const float* __restrict__ Wn,
                                                  u16* __restrict__ Apack) {
    int tid = threadIdx.x;
    float m = partial[tid];
    #pragma unroll
    for (int off = 32; off > 0; off >>= 1) m = fmaxf(m, __shfl_xor(m, off));
    __shared__ float s[4];
    if ((tid & 63) == 0) s[tid >> 6] = m;
    __syncthreads();
    const float mx = fmaxf(fmaxf(s[0], s[1]), fmaxf(s[2], s[3]));
    const float wn = Wn[0];

    int idx = blockIdx.x * 256 + tid;          // ((co*128+ci)*9+tap)
    float nw = w[idx] / mx;
    float q  = (nw > -THRESH && nw <= THRESH) ? 0.0f : nw;
    if (q >  THRESH) q =  1.0f;
    if (q < -THRESH) q = -1.0f;
    if (q == -1.0f)  q = wn;

    int tap = idx % 9;
    int r   = idx / 9;
    int ci  = r % CIN;
    int co  = r / CIN;
    int cc  = ci >> 5, lci = ci & 31, g = lci >> 3, e = lci & 7;
    int cot = co >> 6, row = co & 63;
    int swz = g ^ ((row >> 1) & 3);
    Apack[(size_t)((cc * 4 + cot) * 64 + row) * 288 + tap * 32 + swz * 8 + e] = f2bf(q);
}

// ---------------------------------------------------------------------------
// Kernel 3: zero the borders of padded Xt  (rows/cols 0 and 57)
// grid = 32, block = 256.  228 border sites x 16 chunks of 16B each.
// ---------------------------------------------------------------------------
__global__ __launch_bounds__(256) void xpad_zero(u16* __restrict__ XtP) {
    const int n = blockIdx.x;
    for (int idx = threadIdx.x; idx < 3648; idx += 256) {
        int c16 = idx & 15, s = idx >> 4;
        int r, c;
        if      (s < 58)  { r = 0;           c = s; }
        else if (s < 116) { r = 57;          c = s - 58; }
        else if (s < 172) { r = s - 116 + 1; c = 0; }
        else              { r = s - 172 + 1; c = 57; }
        size_t site = (size_t)(n * PADW + r) * PADW + c;
        *(s16x8*)(XtP + site * 128 + c16 * 8) = (s16x8){0,0,0,0,0,0,0,0};
    }
}

// ---------------------------------------------------------------------------
// Kernel 4: X (NCHW f32) -> padded Xt[n][1+h][1+w][ci] bf16 via LDS transpose
// grid = 32*49, block = 256
// ---------------------------------------------------------------------------
__global__ __launch_bounds__(256) void x_to_bf16t(const float* __restrict__ X,
                                                  u16* __restrict__ XtP) {
    __shared__ u16 T[64 * 136];
    const int b  = blockIdx.x;
    const int n  = b / 49, pt = b - n * 49;
    const int p0 = pt * 64;
    const int tid = threadIdx.x;
    const int ci  = tid >> 1, h2 = tid & 1;

    const float* src = X + ((size_t)(n * CIN + ci)) * HWSZ + p0 + h2 * 32;
    #pragma unroll
    for (int j = 0; j < 8; ++j) {
        f32x4 v = *(const f32x4*)(src + j * 4);
        #pragma unroll
        for (int mth = 0; mth < 4; ++mth)
            T[(h2 * 32 + j * 4 + mth) * 136 + ci] = f2bf(v[mth]);
    }
    __syncthreads();
    #pragma unroll
    for (int k = 0; k < 4; ++k) {
        int idx = tid + k * 256;
        int p = idx >> 4, c8 = idx & 15;
        int gp = p0 + p;
        int h = gp / 56, w = gp - h * 56;
        size_t site = (size_t)(n * PADW + 1 + h) * PADW + 1 + w;
        *(s16x8*)(XtP + site * 128 + c8 * 8) = *(const s16x8*)&T[p * 136 + c8 * 8];
    }
}

// ---------------------------------------------------------------------------
// Kernel 5: implicit-GEMM conv, 512 thr / 8 waves, tile 64 co x 8 rows.
// Wave w owns output row h0+w. K-chunks: cc = ci/32 (9 taps x 32 ci each).
// Staging: global_load_lds width 16, linear LDS, g-permutation on source +
// read (both-sides swizzle). XCD-aware block swizzle: each XCD owns 4 images.
// ---------------------------------------------------------------------------
__global__ __launch_bounds__(512, 4) void conv_mfma(const u16* __restrict__ XtP,
                                                    const u16* __restrict__ Apack,
                                                    float* __restrict__ out) {
    __shared__ u16 Alds[2304 * 8];     // 36,864 B : [64 row][288 k] linear
    __shared__ u16 Xlds[2560 * 8];     // 40,960 B : [<=640 site][32 ci] linear

    const int tid  = threadIdx.x;
    const int wid  = tid >> 6;
    const int lane = tid & 63;
    const int r16  = lane & 15;
    const int g    = lane >> 4;

    // XCD swizzle: 896 blocks, 112 per XCD -> XCD x owns images 4x..4x+3
    const int bid = blockIdx.x;
    const int s   = (bid & 7) * 112 + (bid >> 3);
    const int n   = s / 28;
    const int rem = s - n * 28;
    const int by  = rem >> 2;
    const int bx  = rem & 3;
    const int co0 = bx * 64;
    const int h0  = by * 8;

    f32x4 acc[4][4];
    #pragma unroll
    for (int i = 0; i < 4; ++i)
        #pragma unroll
        for (int j = 0; j < 4; ++j) acc[i][j] = (f32x4){0.f, 0.f, 0.f, 0.f};

    // ---- precompute B-staging source offsets (u16 units, sans cc term) ----
    const int hbase = n * PADW + h0;
    unsigned int bsrc[5];
    #pragma unroll
    for (int i = 0; i < 5; ++i) {
        int p  = i * 512 + tid;
        int pc = (p < 2320) ? p : (p - 2320);       // clamp tail to valid sites
        int site = pc >> 2, gg = pc & 3;
        int r = site / 58, c = site - r * 58;
        int g2 = gg ^ ((site >> 1) & 3);
        bsrc[i] = (unsigned)(((hbase + r) * PADW + c) * 128 + g2 * 8);
    }
    // ---- precompute A-fragment LDS bases (per mf) ----
    int abase[4];
    #pragma unroll
    for (int mf = 0; mf < 4; ++mf) {
        int row = mf * 16 + r16;
        abase[mf] = row * 288 + ((g ^ ((row >> 1) & 3)) << 3);
    }

    for (int cc = 0; cc < 4; ++cc) {
        // ---- stage A: 2304 chunks of 16B, contiguous copy ----
        const u16* asrc = Apack + (size_t)(cc * 4 + bx) * 18432;
        #pragma unroll
        for (int i = 0; i < 4; ++i) {
            int p = i * 512 + tid;
            GLOAD16(asrc + (size_t)p * 8, Alds + (size_t)(i * 512 + wid * 64) * 8);
        }
        if (wid < 4) {
            int p = 2048 + wid * 64 + lane;
            GLOAD16(asrc + (size_t)p * 8, Alds + (size_t)(2048 + wid * 64) * 8);
        }
        // ---- stage B: 2560 chunks (2320 real + 240 clamped dup) ----
        #pragma unroll
        for (int i = 0; i < 5; ++i) {
            GLOAD16(XtP + (size_t)bsrc[i] + cc * 32,
                    Xlds + (size_t)(i * 512 + wid * 64) * 8);
        }
        __syncthreads();   // vmcnt(0) drain + barrier

        // ---- compute: 9 taps x (4 A-frags, 4x(B-frag + 4 MFMA)) ----
        #pragma unroll
        for (int t = 0; t < 9; ++t) {
            const int dh = t / 3, dw = t % 3;
            s16x8 af[4];
            #pragma unroll
            for (int mf = 0; mf < 4; ++mf)
                af[mf] = *(const s16x8*)(Alds + abase[mf] + t * 32);
            #pragma unroll
            for (int nf = 0; nf < 4; ++nf) {
                int site = (wid + dh) * 58 + nf * 16 + r16 + dw;
                int off  = site * 32 + ((g ^ ((site >> 1) & 3)) << 3);
                s16x8 bf = *(const s16x8*)(Xlds + off);
                #pragma unroll
                for (int mf = 0; mf < 4; ++mf)
                    acc[mf][nf] = __builtin_amdgcn_mfma_f32_16x16x32_bf16(
                        af[mf], bf, acc[mf][nf], 0, 0, 0);
            }
        }
        __syncthreads();
    }

    // ---- store: D col = r16 (spatial), row = g*4+j (co) ----
    const int h = h0 + wid;
    float* obase = out + ((size_t)(n * COUT + co0)) * HWSZ + h * WW;
    #pragma unroll
    for (int mf = 0; mf < 4; ++mf)
        #pragma unroll
        for (int nf = 0; nf < 4; ++nf) {
            int col = nf * 16 + r16;
            if (col < WW) {
                #pragma unroll
                for (int j = 0; j < 4; ++j) {
                    int co = mf * 16 + g * 4 + j;
                    obase[(size_t)co * HWSZ + col] = acc[mf][nf][j];
                }
            }
        }
}

// ---------------------------------------------------------------------------
// Launch
// ---------------------------------------------------------------------------
extern "C" void kernel_launch(void* const* d_in, const int* in_sizes, int n_in,
                              void* d_out, int out_size, void* d_ws, size_t ws_size,
                              hipStream_t stream) {
    const float* X      = (const float*)d_in[0];
    const float* weight = (const float*)d_in[1];
    // Wp (d_in[2]) never enters the forward (faithful to source)
    const float* Wn     = (const float*)d_in[3];
    float* out = (float*)d_out;

    float* ws_partial = (float*)d_ws;                        // 256 f32
    u16*   ws_apack   = (u16*)((char*)d_ws + 4096);          // 294912 u16
    u16*   ws_xtp     = (u16*)((char*)d_ws + (1 << 20));     // 32*3364*128 u16 (~27.5 MB)

    maxabs_part<<<256, 256, 0, stream>>>(weight, ws_partial);
    quant_pack<<<WELEM / 256, 256, 0, stream>>>(weight, ws_partial, Wn, ws_apack);
    xpad_zero<<<B_, 256, 0, stream>>>(ws_xtp);
    x_to_bf16t<<<B_ * (HWSZ / 64), 256, 0, stream>>>(X, ws_xtp);

    conv_mfma<<<896, 512, 0, stream>>>(ws_xtp, ws_apack, out);
}

// Round 4
// 100.869 us; speedup vs baseline: 1.0754x; 1.0754x over previous
//
#include <hip/hip_runtime.h>
#include <hip/hip_bf16.h>

#define THRESH 0.05f
constexpr int B_   = 32;
constexpr int CIN  = 128;
constexpr int COUT = 256;
constexpr int HH   = 56;
constexpr int WW   = 56;
constexpr int HWSZ = HH * WW;            // 3136
constexpr int WELEM = COUT * CIN * 9;    // 294912
constexpr int PADW = 58;                 // padded spatial dim

typedef unsigned short u16;
typedef __attribute__((ext_vector_type(4))) float  f32x4;
typedef __attribute__((ext_vector_type(8))) short  s16x8;

typedef const __attribute__((address_space(1))) void* gas1;
typedef __attribute__((address_space(3))) void* las3;
#define GLOAD16(gsrc, ldst) \
    __builtin_amdgcn_global_load_lds((gas1)(gsrc), (las3)(ldst), 16, 0, 0)

static __device__ __forceinline__ u16 f2bf(float f) {
    __hip_bfloat16 h = __float2bfloat16(f);
    return *reinterpret_cast<u16*>(&h);
}

// ---------------------------------------------------------------------------
// Kernel 1: per-block maxabs partials
// ---------------------------------------------------------------------------
__global__ __launch_bounds__(256) void maxabs_part(const float* __restrict__ w,
                                                   float* __restrict__ partial) {
    int tid = threadIdx.x;
    float m = 0.0f;
    for (int i = blockIdx.x * 256 + tid; i < WELEM; i += 256 * 256)
        m = fmaxf(m, fabsf(w[i]));
    #pragma unroll
    for (int off = 32; off > 0; off >>= 1) m = fmaxf(m, __shfl_xor(m, off));
    __shared__ float s[4];
    if ((tid & 63) == 0) s[tid >> 6] = m;
    __syncthreads();
    if (tid == 0) partial[blockIdx.x] = fmaxf(fmaxf(s[0], s[1]), fmaxf(s[2], s[3]));
}

// ---------------------------------------------------------------------------
// Kernel 2: reduce + faithful ternary quantize + pack bf16 into PERMUTED layout
// Apack u16 index: ((cc*4 + cot)*64 + row)*288 + tap*32 + (g ^ ((row>>1)&3))*8 + e
// ---------------------------------------------------------------------------
__global__ __launch_bounds__(256) void quant_pack(const float* __restrict__ w,
                                                  const float* __restrict__ partial,
                                                  const float* __restrict__ Wn,
                                                  u16* __restrict__ Apack) {
    int tid = threadIdx.x;
    float m = partial[tid];
    #pragma unroll
    for (int off = 32; off > 0; off >>= 1) m = fmaxf(m, __shfl_xor(m, off));
    __shared__ float s[4];
    if ((tid & 63) == 0) s[tid >> 6] = m;
    __syncthreads();
    const float mx = fmaxf(fmaxf(s[0], s[1]), fmaxf(s[2], s[3]));
    const float wn = Wn[0];

    int idx = blockIdx.x * 256 + tid;          // ((co*128+ci)*9+tap)
    float nw = w[idx] / mx;
    float q  = (nw > -THRESH && nw <= THRESH) ? 0.0f : nw;
    if (q >  THRESH) q =  1.0f;
    if (q < -THRESH) q = -1.0f;
    if (q == -1.0f)  q = wn;

    int tap = idx % 9;
    int r   = idx / 9;
    int ci  = r % CIN;
    int co  = r / CIN;
    int cc  = ci >> 5, lci = ci & 31, g = lci >> 3, e = lci & 7;
    int cot = co >> 6, row = co & 63;
    int swz = g ^ ((row >> 1) & 3);
    Apack[(size_t)((cc * 4 + cot) * 64 + row) * 288 + tap * 32 + swz * 8 + e] = f2bf(q);
}

// ---------------------------------------------------------------------------
// Kernel 3: zero the borders of padded Xt
// ---------------------------------------------------------------------------
__global__ __launch_bounds__(256) void xpad_zero(u16* __restrict__ XtP) {
    const int n = blockIdx.x;
    for (int idx = threadIdx.x; idx < 3648; idx += 256) {
        int c16 = idx & 15, s = idx >> 4;
        int r, c;
        if      (s < 58)  { r = 0;           c = s; }
        else if (s < 116) { r = 57;          c = s - 58; }
        else if (s < 172) { r = s - 116 + 1; c = 0; }
        else              { r = s - 172 + 1; c = 57; }
        size_t site = (size_t)(n * PADW + r) * PADW + c;
        *(s16x8*)(XtP + site * 128 + c16 * 8) = (s16x8){0,0,0,0,0,0,0,0};
    }
}

// ---------------------------------------------------------------------------
// Kernel 4: X (NCHW f32) -> padded Xt[n][1+h][1+w][ci] bf16 via LDS transpose
// ---------------------------------------------------------------------------
__global__ __launch_bounds__(256) void x_to_bf16t(const float* __restrict__ X,
                                                  u16* __restrict__ XtP) {
    __shared__ u16 T[64 * 136];
    const int b  = blockIdx.x;
    const int n  = b / 49, pt = b - n * 49;
    const int p0 = pt * 64;
    const int tid = threadIdx.x;
    const int ci  = tid >> 1, h2 = tid & 1;

    const float* src = X + ((size_t)(n * CIN + ci)) * HWSZ + p0 + h2 * 32;
    #pragma unroll
    for (int j = 0; j < 8; ++j) {
        f32x4 v = *(const f32x4*)(src + j * 4);
        #pragma unroll
        for (int mth = 0; mth < 4; ++mth)
            T[(h2 * 32 + j * 4 + mth) * 136 + ci] = f2bf(v[mth]);
    }
    __syncthreads();
    #pragma unroll
    for (int k = 0; k < 4; ++k) {
        int idx = tid + k * 256;
        int p = idx >> 4, c8 = idx & 15;
        int gp = p0 + p;
        int h = gp / 56, w = gp - h * 56;
        size_t site = (size_t)(n * PADW + 1 + h) * PADW + 1 + w;
        *(s16x8*)(XtP + site * 128 + c8 * 8) = *(const s16x8*)&T[p * 136 + c8 * 8];
    }
}

// ---------------------------------------------------------------------------
// Kernel 5: implicit-GEMM conv — 9-tap phased schedule (T3+T4+T5).
// 512 thr / 8 waves, tile 64 co x 8 rows, double-buffered LDS (152 KB).
// Per cc-chunk: 9 phases {8x ds_read_b128 || stage-issue nxt -> barrier ->
// lgkmcnt(0) -> setprio(1) 16 MFMA setprio(0) -> barrier}. Staging for
// chunk cc+1 issued at phases 0-4 (issue-early), vmcnt(0) drain only at the
// chunk boundary (drain-late: ~4.5 phases of compute cover the L2 latency).
// ---------------------------------------------------------------------------
__global__ __launch_bounds__(512, 2) void conv_mfma(const u16* __restrict__ XtP,
                                                    const u16* __restrict__ Apack,
                                                    float* __restrict__ out) {
    __shared__ u16 Alds[2][18432];     // 2 x 36,864 B : [64 row][288 k] linear
    __shared__ u16 Xlds[2][20480];     // 2 x 40,960 B : [640 site][32 ci] linear

    const int tid  = threadIdx.x;
    const int wid  = tid >> 6;
    const int lane = tid & 63;
    const int r16  = lane & 15;
    const int g    = lane >> 4;

    // XCD swizzle: 896 blocks, 112 per XCD -> XCD x owns images 4x..4x+3
    const int bid = blockIdx.x;
    const int s   = (bid & 7) * 112 + (bid >> 3);
    const int n   = s / 28;
    const int rem = s - n * 28;
    const int by  = rem >> 2;
    const int bx  = rem & 3;
    const int co0 = bx * 64;
    const int h0  = by * 8;

    f32x4 acc[4][4];
    #pragma unroll
    for (int i = 0; i < 4; ++i)
        #pragma unroll
        for (int j = 0; j < 4; ++j) acc[i][j] = (f32x4){0.f, 0.f, 0.f, 0.f};

    // ---- precompute B-staging source offsets (u16 units, sans cc term) ----
    const int hbase = n * PADW + h0;
    unsigned int bsrc[5];
    #pragma unroll
    for (int i = 0; i < 5; ++i) {
        int p  = i * 512 + tid;
        int pc = (p < 2320) ? p : (p - 2320);       // clamp tail to valid sites
        int site = pc >> 2, gg = pc & 3;
        int r = site / 58, c = site - r * 58;
        int g2 = gg ^ ((site >> 1) & 3);
        bsrc[i] = (unsigned)(((hbase + r) * PADW + c) * 128 + g2 * 8);
    }
    // ---- precompute A-fragment LDS bases (per mf, u16 units) ----
    int abase[4];
    #pragma unroll
    for (int mf = 0; mf < 4; ++mf) {
        int row = mf * 16 + r16;
        abase[mf] = row * 288 + ((g ^ ((row >> 1) & 3)) << 3);
    }

    // ---- prologue: stage chunk 0 into buffer 0, full drain ----
    {
        const u16* asrc = Apack + (size_t)bx * 18432;
        #pragma unroll
        for (int i = 0; i < 4; ++i)
            GLOAD16(asrc + (size_t)(i * 512 + tid) * 8, &Alds[0][(i * 512 + wid * 64) * 8]);
        if (wid < 4)
            GLOAD16(asrc + (size_t)(2048 + wid * 64 + lane) * 8, &Alds[0][(2048 + wid * 64) * 8]);
        #pragma unroll
        for (int i = 0; i < 5; ++i)
            GLOAD16(XtP + (size_t)bsrc[i], &Xlds[0][(i * 512 + wid * 64) * 8]);
        asm volatile("s_waitcnt vmcnt(0)" ::: "memory");
        __builtin_amdgcn_s_barrier();
        __builtin_amdgcn_sched_barrier(0);
    }

    for (int cc = 0; cc < 4; ++cc) {
        const int cur = cc & 1;
        const int nxt = cur ^ 1;
        const u16* asrc_n = Apack + (size_t)((cc + 1) * 4 + bx) * 18432;

        #pragma unroll
        for (int t = 0; t < 9; ++t) {
            const int dh = t / 3, dw = t % 3;

            // ---- ds_read current-buffer fragments for tap t ----
            s16x8 af[4], bfr[4];
            #pragma unroll
            for (int mf = 0; mf < 4; ++mf)
                af[mf] = *(const s16x8*)&Alds[cur][abase[mf] + t * 32];
            #pragma unroll
            for (int nf = 0; nf < 4; ++nf) {
                int site = (wid + dh) * 58 + nf * 16 + r16 + dw;
                int off  = site * 32 + ((g ^ ((site >> 1) & 3)) << 3);
                bfr[nf] = *(const s16x8*)&Xlds[nxt ^ 1 ^ nxt][0]; // placeholder avoided below
                bfr[nf] = *(const s16x8*)&Xlds[cur][off];
            }

            // ---- stage-issue chunk cc+1 (phases 0..4 only) ----
            if (cc < 3) {
                if (t < 4) {
                    GLOAD16(asrc_n + (size_t)(t * 512 + tid) * 8,
                            &Alds[nxt][(t * 512 + wid * 64) * 8]);
                    GLOAD16(XtP + (size_t)bsrc[t] + (cc + 1) * 32,
                            &Xlds[nxt][(t * 512 + wid * 64) * 8]);
                } else if (t == 4) {
                    if (wid < 4)
                        GLOAD16(asrc_n + (size_t)(2048 + wid * 64 + lane) * 8,
                                &Alds[nxt][(2048 + wid * 64) * 8]);
                    GLOAD16(XtP + (size_t)bsrc[4] + (cc + 1) * 32,
                            &Xlds[nxt][(4 * 512 + wid * 64) * 8]);
                }
            }

            __builtin_amdgcn_s_barrier();
            asm volatile("s_waitcnt lgkmcnt(0)" ::: "memory");
            __builtin_amdgcn_sched_barrier(0);
            __builtin_amdgcn_s_setprio(1);
            #pragma unroll
            for (int mf = 0; mf < 4; ++mf)
                #pragma unroll
                for (int nf = 0; nf < 4; ++nf)
                    acc[mf][nf] = __builtin_amdgcn_mfma_f32_16x16x32_bf16(
                        af[mf], bfr[nf], acc[mf][nf], 0, 0, 0);
            __builtin_amdgcn_s_setprio(0);
            __builtin_amdgcn_sched_barrier(0);
            __builtin_amdgcn_s_barrier();
        }

        // ---- chunk boundary: drain our own staging loads, re-sync ----
        if (cc < 3) {
            asm volatile("s_waitcnt vmcnt(0)" ::: "memory");
            __builtin_amdgcn_s_barrier();
            __builtin_amdgcn_sched_barrier(0);
        }
    }

    // ---- store: D col = r16 (spatial), row = g*4+j (co) ----
    const int h = h0 + wid;
    float* obase = out + ((size_t)(n * COUT + co0)) * HWSZ + h * WW;
    #pragma unroll
    for (int mf = 0; mf < 4; ++mf)
        #pragma unroll
        for (int nf = 0; nf < 4; ++nf) {
            int col = nf * 16 + r16;
            if (col < WW) {
                #pragma unroll
                for (int j = 0; j < 4; ++j) {
                    int co = mf * 16 + g * 4 + j;
                    obase[(size_t)co * HWSZ + col] = acc[mf][nf][j];
                }
            }
        }
}

// ---------------------------------------------------------------------------
// Launch
// ---------------------------------------------------------------------------
extern "C" void kernel_launch(void* const* d_in, const int* in_sizes, int n_in,
                              void* d_out, int out_size, void* d_ws, size_t ws_size,
                              hipStream_t stream) {
    const float* X      = (const float*)d_in[0];
    const float* weight = (const float*)d_in[1];
    // Wp (d_in[2]) never enters the forward (faithful to source)
    const float* Wn     = (const float*)d_in[3];
    float* out = (float*)d_out;

    float* ws_partial = (float*)d_ws;                        // 256 f32
    u16*   ws_apack   = (u16*)((char*)d_ws + 4096);          // 294912 u16
    u16*   ws_xtp     = (u16*)((char*)d_ws + (1 << 20));     // 32*3364*128 u16 (~27.5 MB)

    maxabs_part<<<256, 256, 0, stream>>>(weight, ws_partial);
    quant_pack<<<WELEM / 256, 256, 0, stream>>>(weight, ws_partial, Wn, ws_apack);
    xpad_zero<<<B_, 256, 0, stream>>>(ws_xtp);
    x_to_bf16t<<<B_ * (HWSZ / 64), 256, 0, stream>>>(X, ws_xtp);

    conv_mfma<<<896, 512, 0, stream>>>(ws_xtp, ws_apack, out);
}

// Round 5
// 95.576 us; speedup vs baseline: 1.1349x; 1.0554x over previous
//
#include <hip/hip_runtime.h>
#include <hip/hip_bf16.h>

#define THRESH 0.05f
constexpr int B_   = 32;
constexpr int CIN  = 128;
constexpr int COUT = 256;
constexpr int HH   = 56;
constexpr int WW   = 56;
constexpr int HWSZ = HH * WW;            // 3136
constexpr int WELEM = COUT * CIN * 9;    // 294912
constexpr int PADW = 58;                 // padded spatial dim

typedef unsigned short u16;
typedef __attribute__((ext_vector_type(4))) float  f32x4;
typedef __attribute__((ext_vector_type(8))) short  s16x8;

typedef const __attribute__((address_space(1))) void* gas1;
typedef __attribute__((address_space(3))) void* las3;
#define GLOAD16(gsrc, ldst) \
    __builtin_amdgcn_global_load_lds((gas1)(gsrc), (las3)(ldst), 16, 0, 0)

static __device__ __forceinline__ u16 f2bf(float f) {
    __hip_bfloat16 h = __float2bfloat16(f);
    return *reinterpret_cast<u16*>(&h);
}

// ---------------------------------------------------------------------------
// Kernel 1: per-block maxabs partials
// ---------------------------------------------------------------------------
__global__ __launch_bounds__(256) void maxabs_part(const float* __restrict__ w,
                                                   float* __restrict__ partial) {
    int tid = threadIdx.x;
    float m = 0.0f;
    for (int i = blockIdx.x * 256 + tid; i < WELEM; i += 256 * 256)
        m = fmaxf(m, fabsf(w[i]));
    #pragma unroll
    for (int off = 32; off > 0; off >>= 1) m = fmaxf(m, __shfl_xor(m, off));
    __shared__ float s[4];
    if ((tid & 63) == 0) s[tid >> 6] = m;
    __syncthreads();
    if (tid == 0) partial[blockIdx.x] = fmaxf(fmaxf(s[0], s[1]), fmaxf(s[2], s[3]));
}

// ---------------------------------------------------------------------------
// Kernel 2: reduce + faithful ternary quantize + pack bf16 into PERMUTED layout
// Apack u16 index: ((cc*4 + cot)*64 + row)*288 + tap*32 + (g ^ ((row>>1)&3))*8 + e
// ---------------------------------------------------------------------------
__global__ __launch_bounds__(256) void quant_pack(const float* __restrict__ w,
                                                  const float* __restrict__ partial,
                                                  const float* __restrict__ Wn,
                                                  u16* __restrict__ Apack) {
    int tid = threadIdx.x;
    float m = partial[tid];
    #pragma unroll
    for (int off = 32; off > 0; off >>= 1) m = fmaxf(m, __shfl_xor(m, off));
    __shared__ float s[4];
    if ((tid & 63) == 0) s[tid >> 6] = m;
    __syncthreads();
    const float mx = fmaxf(fmaxf(s[0], s[1]), fmaxf(s[2], s[3]));
    const float wn = Wn[0];

    int idx = blockIdx.x * 256 + tid;          // ((co*128+ci)*9+tap)
    float nw = w[idx] / mx;
    float q  = (nw > -THRESH && nw <= THRESH) ? 0.0f : nw;
    if (q >  THRESH) q =  1.0f;
    if (q < -THRESH) q = -1.0f;
    if (q == -1.0f)  q = wn;

    int tap = idx % 9;
    int r   = idx / 9;
    int ci  = r % CIN;
    int co  = r / CIN;
    int cc  = ci >> 5, lci = ci & 31, g = lci >> 3, e = lci & 7;
    int cot = co >> 6, row = co & 63;
    int swz = g ^ ((row >> 1) & 3);
    Apack[(size_t)((cc * 4 + cot) * 64 + row) * 288 + tap * 32 + swz * 8 + e] = f2bf(q);
}

// ---------------------------------------------------------------------------
// Kernel 3: zero the borders of padded Xt
// ---------------------------------------------------------------------------
__global__ __launch_bounds__(256) void xpad_zero(u16* __restrict__ XtP) {
    const int n = blockIdx.x;
    for (int idx = threadIdx.x; idx < 3648; idx += 256) {
        int c16 = idx & 15, s = idx >> 4;
        int r, c;
        if      (s < 58)  { r = 0;           c = s; }
        else if (s < 116) { r = 57;          c = s - 58; }
        else if (s < 172) { r = s - 116 + 1; c = 0; }
        else              { r = s - 172 + 1; c = 57; }
        size_t site = (size_t)(n * PADW + r) * PADW + c;
        *(s16x8*)(XtP + site * 128 + c16 * 8) = (s16x8){0,0,0,0,0,0,0,0};
    }
}

// ---------------------------------------------------------------------------
// Kernel 4: X (NCHW f32) -> padded Xt[n][1+h][1+w][ci] bf16 via LDS transpose
// ---------------------------------------------------------------------------
__global__ __launch_bounds__(256) void x_to_bf16t(const float* __restrict__ X,
                                                  u16* __restrict__ XtP) {
    __shared__ u16 T[64 * 136];
    const int b  = blockIdx.x;
    const int n  = b / 49, pt = b - n * 49;
    const int p0 = pt * 64;
    const int tid = threadIdx.x;
    const int ci  = tid >> 1, h2 = tid & 1;

    const float* src = X + ((size_t)(n * CIN + ci)) * HWSZ + p0 + h2 * 32;
    #pragma unroll
    for (int j = 0; j < 8; ++j) {
        f32x4 v = *(const f32x4*)(src + j * 4);
        #pragma unroll
        for (int mth = 0; mth < 4; ++mth)
            T[(h2 * 32 + j * 4 + mth) * 136 + ci] = f2bf(v[mth]);
    }
    __syncthreads();
    #pragma unroll
    for (int k = 0; k < 4; ++k) {
        int idx = tid + k * 256;
        int p = idx >> 4, c8 = idx & 15;
        int gp = p0 + p;
        int h = gp / 56, w = gp - h * 56;
        size_t site = (size_t)(n * PADW + 1 + h) * PADW + 1 + w;
        *(s16x8*)(XtP + site * 128 + c8 * 8) = *(const s16x8*)&T[p * 136 + c8 * 8];
    }
}

// ---------------------------------------------------------------------------
// Kernel 5: implicit-GEMM conv — ONE barrier per cc-chunk.
// 512 thr / 8 waves, tile 64 co x 8 rows, double-buffered LDS (152 KB).
// Per chunk: issue all glds for chunk cc+1 into the other buffer, then stream
// 9 taps (72 ds_read_b128 + 144 MFMA) with NO intra-chunk barriers (compiler
// emits fine lgkmcnt and pipelines reads under the matrix pipe), then
// vmcnt(0) + one s_barrier, flip. XOR-swizzle term is mf/nf-invariant, so
// all ds_read addresses are 2 base VGPRs + 9 tap offsets + immediates.
// ---------------------------------------------------------------------------
__global__ __launch_bounds__(512, 2) void conv_mfma(const u16* __restrict__ XtP,
                                                    const u16* __restrict__ Apack,
                                                    float* __restrict__ out) {
    __shared__ u16 Alds[2][18432];     // 2 x 36,864 B : [64 row][288 k] linear
    __shared__ u16 Xlds[2][20480];     // 2 x 40,960 B : [640 site][32 ci] linear

    const int tid  = threadIdx.x;
    const int wid  = tid >> 6;
    const int lane = tid & 63;
    const int r16  = lane & 15;
    const int g    = lane >> 4;

    // XCD swizzle: 896 blocks, 112 per XCD -> XCD x owns images 4x..4x+3
    const int bid = blockIdx.x;
    const int s   = (bid & 7) * 112 + (bid >> 3);
    const int n   = s / 28;
    const int rem = s - n * 28;
    const int by  = rem >> 2;
    const int bx  = rem & 3;
    const int co0 = bx * 64;
    const int h0  = by * 8;

    f32x4 acc[4][4];
    #pragma unroll
    for (int i = 0; i < 4; ++i)
        #pragma unroll
        for (int j = 0; j < 4; ++j) acc[i][j] = (f32x4){0.f, 0.f, 0.f, 0.f};

    // ---- B-staging source offsets (u16 units, sans cc term) ----
    const int hbase = n * PADW + h0;
    unsigned int bsrc[5];
    #pragma unroll
    for (int i = 0; i < 5; ++i) {
        int p  = i * 512 + tid;
        int pc = (p < 2320) ? p : (p - 2320);       // clamp tail to valid sites
        int site = pc >> 2, gg = pc & 3;
        int r = site / 58, c = site - r * 58;
        int g2 = gg ^ ((site >> 1) & 3);
        bsrc[i] = (unsigned)(((hbase + r) * PADW + c) * 128 + g2 * 8);
    }

    // ---- A fragment base (u16 units): XOR term invariant in mf & tap ----
    //   row = mf*16 + r16 -> (row>>1)&3 == (r16>>1)&3
    const int abase0 = r16 * 288 + ((g ^ ((r16 >> 1) & 3)) << 3);

    // ---- B per-tap offsets (u16 units): XOR term invariant in nf ----
    //   site = base_t + nf*16 -> (site>>1)&3 == (base_t>>1)&3
    int otap[9];
    #pragma unroll
    for (int t = 0; t < 9; ++t) {
        int base_t = (wid + t / 3) * 58 + r16 + (t % 3);
        otap[t] = base_t * 32 + ((g ^ ((base_t >> 1) & 3)) << 3);
    }

    // ---- prologue: stage chunk 0 into buffer 0, full drain ----
    {
        const u16* asrc = Apack + (size_t)bx * 18432;
        #pragma unroll
        for (int i = 0; i < 4; ++i)
            GLOAD16(asrc + (size_t)(i * 512 + tid) * 8, &Alds[0][(i * 512 + wid * 64) * 8]);
        if (wid < 4)
            GLOAD16(asrc + (size_t)(2048 + wid * 64 + lane) * 8, &Alds[0][(2048 + wid * 64) * 8]);
        #pragma unroll
        for (int i = 0; i < 5; ++i)
            GLOAD16(XtP + (size_t)bsrc[i], &Xlds[0][(i * 512 + wid * 64) * 8]);
        asm volatile("s_waitcnt vmcnt(0)" ::: "memory");
        __builtin_amdgcn_s_barrier();
        __builtin_amdgcn_sched_barrier(0);
    }

    #pragma unroll
    for (int cc = 0; cc < 4; ++cc) {
        const int cur = cc & 1;
        const int nxt = cur ^ 1;

        // ---- issue ALL staging for chunk cc+1 first (independent of compute)
        if (cc < 3) {
            const u16* asrc_n = Apack + (size_t)((cc + 1) * 4 + bx) * 18432;
            #pragma unroll
            for (int i = 0; i < 4; ++i)
                GLOAD16(asrc_n + (size_t)(i * 512 + tid) * 8,
                        &Alds[nxt][(i * 512 + wid * 64) * 8]);
            if (wid < 4)
                GLOAD16(asrc_n + (size_t)(2048 + wid * 64 + lane) * 8,
                        &Alds[nxt][(2048 + wid * 64) * 8]);
            #pragma unroll
            for (int i = 0; i < 5; ++i)
                GLOAD16(XtP + (size_t)bsrc[i] + (cc + 1) * 32,
                        &Xlds[nxt][(i * 512 + wid * 64) * 8]);
        }

        // ---- stream 9 taps, no barriers: compiler pipelines lgkmcnt ----
        const u16* Ab = &Alds[cur][abase0];
        const u16* Xb = &Xlds[cur][0];
        #pragma unroll
        for (int t = 0; t < 9; ++t) {
            s16x8 af[4], bfr[4];
            #pragma unroll
            for (int mf = 0; mf < 4; ++mf)
                af[mf] = *(const s16x8*)(Ab + mf * 4608 + t * 32);
            #pragma unroll
            for (int nf = 0; nf < 4; ++nf)
                bfr[nf] = *(const s16x8*)(Xb + otap[t] + nf * 512);
            #pragma unroll
            for (int mf = 0; mf < 4; ++mf)
                #pragma unroll
                for (int nf = 0; nf < 4; ++nf)
                    acc[mf][nf] = __builtin_amdgcn_mfma_f32_16x16x32_bf16(
                        af[mf], bfr[nf], acc[mf][nf], 0, 0, 0);
        }

        // ---- chunk boundary: drain staging, one barrier, flip ----
        if (cc < 3) {
            asm volatile("s_waitcnt vmcnt(0)" ::: "memory");
            __builtin_amdgcn_s_barrier();
            __builtin_amdgcn_sched_barrier(0);
        }
    }

    // ---- store: D col = r16 (spatial), row = g*4+j (co) ----
    const int h = h0 + wid;
    float* obase = out + ((size_t)(n * COUT + co0)) * HWSZ + h * WW;
    #pragma unroll
    for (int mf = 0; mf < 4; ++mf)
        #pragma unroll
        for (int nf = 0; nf < 4; ++nf) {
            int col = nf * 16 + r16;
            if (col < WW) {
                #pragma unroll
                for (int j = 0; j < 4; ++j) {
                    int co = mf * 16 + g * 4 + j;
                    obase[(size_t)co * HWSZ + col] = acc[mf][nf][j];
                }
            }
        }
}

// ---------------------------------------------------------------------------
// Launch
// ---------------------------------------------------------------------------
extern "C" void kernel_launch(void* const* d_in, const int* in_sizes, int n_in,
                              void* d_out, int out_size, void* d_ws, size_t ws_size,
                              hipStream_t stream) {
    const float* X      = (const float*)d_in[0];
    const float* weight = (const float*)d_in[1];
    // Wp (d_in[2]) never enters the forward (faithful to source)
    const float* Wn     = (const float*)d_in[3];
    float* out = (float*)d_out;

    float* ws_partial = (float*)d_ws;                        // 256 f32
    u16*   ws_apack   = (u16*)((char*)d_ws + 4096);          // 294912 u16
    u16*   ws_xtp     = (u16*)((char*)d_ws + (1 << 20));     // 32*3364*128 u16 (~27.5 MB)

    maxabs_part<<<256, 256, 0, stream>>>(weight, ws_partial);
    quant_pack<<<WELEM / 256, 256, 0, stream>>>(weight, ws_partial, Wn, ws_apack);
    xpad_zero<<<B_, 256, 0, stream>>>(ws_xtp);
    x_to_bf16t<<<B_ * (HWSZ / 64), 256, 0, stream>>>(X, ws_xtp);

    conv_mfma<<<896, 512, 0, stream>>>(ws_xtp, ws_apack, out);
}